// Round 1
// baseline (1610.101 us; speedup 1.0000x reference)
//
#include <hip/hip_runtime.h>

#define N_EDGES 1000000
#define N_NODES 500000
#define N_TRIS  600000

// tanh via exp2-based __expf; clamp keeps e^{2z} finite, tanh(15) == 1.0f in f32.
__device__ __forceinline__ float fast_tanh(float z) {
    z = fminf(fmaxf(z, -15.0f), 15.0f);
    float e = __expf(2.0f * z);
    return (e - 1.0f) / (e + 1.0f);
}

// One thread per (edge, channel). x read fully coalesced; 2 atomics into y.
__global__ __launch_bounds__(256) void k_scatter_y(
    const float* __restrict__ x, const int* __restrict__ en, float* __restrict__ y)
{
    int idx = blockIdx.x * 256 + threadIdx.x;
    int e = idx >> 6, c = idx & 63;
    float v = x[idx];
    int tail = en[2 * e];
    int head = en[2 * e + 1];
    unsafeAtomicAdd(&y[(size_t)tail * 64 + c], -v);
    unsafeAtomicAdd(&y[(size_t)head * 64 + c],  v);
}

// One thread per (triangle, channel). 3 row gathers (row-contiguous per wave) + 3 atomics.
__global__ __launch_bounds__(256) void k_scatter_z1e(
    const float* __restrict__ x, const int* __restrict__ te, float* __restrict__ z1e)
{
    int idx = blockIdx.x * 256 + threadIdx.x;
    int t = idx >> 6, c = idx & 63;
    int e0 = te[3 * t], e1 = te[3 * t + 1], e2 = te[3 * t + 2];
    float w = x[(size_t)e0 * 64 + c] - x[(size_t)e1 * 64 + c] + x[(size_t)e2 * 64 + c];
    unsafeAtomicAdd(&z1e[(size_t)e0 * 64 + c],  w);
    unsafeAtomicAdd(&z1e[(size_t)e1 * 64 + c], -w);
    unsafeAtomicAdd(&z1e[(size_t)e2 * 64 + c],  w);
}

// Fused GEMM+epilogue: out = tanh(z1e@w2 + x@w1 + (y[head]-y[tail])@w0).
// 64-edge tile/block, K split into 6 phases of 32 (3 sources x 2 halves).
// zio holds z1e on entry, final output on exit (each block reads/writes only its rows).
__global__ __launch_bounds__(256) void k_final(
    const float* __restrict__ x, const int* __restrict__ en,
    const float* __restrict__ y, float* __restrict__ zio,
    const float* __restrict__ w0, const float* __restrict__ w1,
    const float* __restrict__ w2)
{
    __shared__ float WB[3 * 4096];   // [0]=w2 (z1e), [1]=w1 (x), [2]=w0 (yd)
    __shared__ float AT[32 * 68];    // k-major A chunk, row stride 68 keeps float4 alignment
    __shared__ int   nidx[128];      // [0..63]=tail, [64..127]=head

    const int t = threadIdx.x;
    const int ebase = blockIdx.x * 64;

    for (int i = t; i < 1024; i += 256) {
        ((float4*)WB)[i]        = ((const float4*)w2)[i];
        ((float4*)WB)[1024 + i] = ((const float4*)w1)[i];
        ((float4*)WB)[2048 + i] = ((const float4*)w0)[i];
    }
    if (t < 128) {
        int e = ebase + (t & 63);
        nidx[t] = en[2 * e + (t >> 6)];
    }

    const int r  = t >> 2;   // staging: edge row 0..63
    const int q  = t & 3;    // staging: 8-col group within the 32-col half
    const int tx = t & 15;   // compute: channel group (4 channels)
    const int ty = t >> 4;   // compute: edge group (4 edges)

    float acc[4][4] = {};

    for (int ph = 0; ph < 6; ++ph) {
        const int ch = ph >> 1;
        const int h  = ph & 1;
        float4 v0, v1;
        if (ch == 0) {
            const float4* s = (const float4*)(zio + (size_t)(ebase + r) * 64 + h * 32 + q * 8);
            v0 = s[0]; v1 = s[1];
        } else if (ch == 1) {
            const float4* s = (const float4*)(x + (size_t)(ebase + r) * 64 + h * 32 + q * 8);
            v0 = s[0]; v1 = s[1];
        } else {
            const float4* sh = (const float4*)(y + (size_t)nidx[64 + r] * 64 + h * 32 + q * 8);
            const float4* st = (const float4*)(y + (size_t)nidx[r] * 64 + h * 32 + q * 8);
            float4 a0 = sh[0], a1 = sh[1], b0 = st[0], b1 = st[1];
            v0.x = a0.x - b0.x; v0.y = a0.y - b0.y; v0.z = a0.z - b0.z; v0.w = a0.w - b0.w;
            v1.x = a1.x - b1.x; v1.y = a1.y - b1.y; v1.z = a1.z - b1.z; v1.w = a1.w - b1.w;
        }
        __syncthreads();   // previous phase's compute done reading AT
        AT[(q * 8 + 0) * 68 + r] = v0.x;
        AT[(q * 8 + 1) * 68 + r] = v0.y;
        AT[(q * 8 + 2) * 68 + r] = v0.z;
        AT[(q * 8 + 3) * 68 + r] = v0.w;
        AT[(q * 8 + 4) * 68 + r] = v1.x;
        AT[(q * 8 + 5) * 68 + r] = v1.y;
        AT[(q * 8 + 6) * 68 + r] = v1.z;
        AT[(q * 8 + 7) * 68 + r] = v1.w;
        __syncthreads();   // staged chunk visible (also covers WB/nidx on first pass)
        const float* Wc = WB + ch * 4096 + h * 32 * 64;
        #pragma unroll 8
        for (int k = 0; k < 32; ++k) {
            float4 b = *(const float4*)(Wc + k * 64 + tx * 4);
            float4 a = *(const float4*)(AT + k * 68 + ty * 4);
            acc[0][0] += a.x * b.x; acc[0][1] += a.x * b.y; acc[0][2] += a.x * b.z; acc[0][3] += a.x * b.w;
            acc[1][0] += a.y * b.x; acc[1][1] += a.y * b.y; acc[1][2] += a.y * b.z; acc[1][3] += a.y * b.w;
            acc[2][0] += a.z * b.x; acc[2][1] += a.z * b.y; acc[2][2] += a.z * b.z; acc[2][3] += a.z * b.w;
            acc[3][0] += a.w * b.x; acc[3][1] += a.w * b.y; acc[3][2] += a.w * b.z; acc[3][3] += a.w * b.w;
        }
    }

    #pragma unroll
    for (int i = 0; i < 4; ++i) {
        int e = ebase + ty * 4 + i;
        float4 o;
        o.x = fast_tanh(acc[i][0]);
        o.y = fast_tanh(acc[i][1]);
        o.z = fast_tanh(acc[i][2]);
        o.w = fast_tanh(acc[i][3]);
        *(float4*)(zio + (size_t)e * 64 + tx * 4) = o;
    }
}

extern "C" void kernel_launch(void* const* d_in, const int* in_sizes, int n_in,
                              void* d_out, int out_size, void* d_ws, size_t ws_size,
                              hipStream_t stream) {
    const float* x  = (const float*)d_in[0];
    const int*   en = (const int*)d_in[1];
    const int*   te = (const int*)d_in[2];
    const float* w0 = (const float*)d_in[3];
    const float* w1 = (const float*)d_in[4];
    const float* w2 = (const float*)d_in[5];
    float* out = (float*)d_out;          // doubles as z1e scratch
    float* y   = (float*)d_ws;           // 128 MB

    hipMemsetAsync(y,   0, (size_t)N_NODES * 64 * sizeof(float), stream);
    hipMemsetAsync(out, 0, (size_t)N_EDGES * 64 * sizeof(float), stream);

    k_scatter_y  <<<(N_EDGES * 64) / 256, 256, 0, stream>>>(x, en, y);
    k_scatter_z1e<<<(N_TRIS  * 64) / 256, 256, 0, stream>>>(x, te, out);
    k_final      <<<N_EDGES / 64,        256, 0, stream>>>(x, en, y, out, w0, w1, w2);
}

// Round 2
// 1594.701 us; speedup vs baseline: 1.0097x; 1.0097x over previous
//
#include <hip/hip_runtime.h>
#include <hip/hip_bf16.h>

#define N_EDGES 1000000
#define N_NODES 500000
#define N_TRIS  600000

typedef __attribute__((ext_vector_type(8))) short bf16x8;
typedef __attribute__((ext_vector_type(4))) float f32x4;

// tanh via exp2-based __expf; clamp keeps e^{2z} finite, tanh(15) == 1.0f in f32.
__device__ __forceinline__ float fast_tanh(float z) {
    z = fminf(fmaxf(z, -15.0f), 15.0f);
    float e = __expf(2.0f * z);
    return (e - 1.0f) / (e + 1.0f);
}

// One thread per (edge, channel). x read fully coalesced; 2 atomics into y.
__global__ __launch_bounds__(256) void k_scatter_y(
    const float* __restrict__ x, const int* __restrict__ en, float* __restrict__ y)
{
    int idx = blockIdx.x * 256 + threadIdx.x;
    int e = idx >> 6, c = idx & 63;
    float v = x[idx];
    int tail = en[2 * e];
    int head = en[2 * e + 1];
    unsafeAtomicAdd(&y[(size_t)tail * 64 + c], -v);
    unsafeAtomicAdd(&y[(size_t)head * 64 + c],  v);
}

// One thread per (triangle, channel). 3 row gathers (row-contiguous per wave) + 3 atomics.
__global__ __launch_bounds__(256) void k_scatter_z1e(
    const float* __restrict__ x, const int* __restrict__ te, float* __restrict__ z1e)
{
    int idx = blockIdx.x * 256 + threadIdx.x;
    int t = idx >> 6, c = idx & 63;
    int e0 = te[3 * t], e1 = te[3 * t + 1], e2 = te[3 * t + 2];
    float w = x[(size_t)e0 * 64 + c] - x[(size_t)e1 * 64 + c] + x[(size_t)e2 * 64 + c];
    unsafeAtomicAdd(&z1e[(size_t)e0 * 64 + c],  w);
    unsafeAtomicAdd(&z1e[(size_t)e1 * 64 + c], -w);
    unsafeAtomicAdd(&z1e[(size_t)e2 * 64 + c],  w);
}

// Fused split-bf16 MFMA GEMM + tanh epilogue:
//   out = tanh([z1e | x | y_head - y_tail] @ [w2; w1; w0])   (K = 192, N = 64)
// Split: A ~= A_hi + A_lo, W ~= W_hi + W_lo (bf16); compute HiHi + LoHi + HiLo
// (LoLo ~ 2^-18 relative, dropped). 64-edge tile/block; 4 waves; wave w owns
// rows [w*16, w*16+16), 4 N-tiles of 16 each -> 12 MFMAs per K=32 chunk.
#define AST 48    // A LDS row stride in bf16 (96 B: 16B-aligned, 4-way alias only)
#define WST 200   // WT LDS row stride in bf16 (400 B: 16B-aligned, 2-way alias = free)

__global__ __launch_bounds__(256) void k_final(
    const float* __restrict__ x, const int* __restrict__ en,
    const float* __restrict__ y, float* __restrict__ zio,
    const float* __restrict__ w0, const float* __restrict__ w1,
    const float* __restrict__ w2)
{
    __shared__ __hip_bfloat16 WThi[64 * WST];  // WT[n][k], k: 0..63=w2, 64..127=w1, 128..191=w0
    __shared__ __hip_bfloat16 WTlo[64 * WST];
    __shared__ __hip_bfloat16 Ahi[64 * AST];   // A chunk [row][k_local 0..31]
    __shared__ __hip_bfloat16 Alo[64 * AST];
    __shared__ int nidx[128];                  // [0..63]=tail, [64..127]=head

    const int t = threadIdx.x;
    const int ebase = blockIdx.x * 64;

    // Stage W transposed, split hi/lo. Coalesced global reads (n contiguous).
    for (int idx = t; idx < 12288; idx += 256) {
        int k = idx >> 6;           // 0..191
        int n = idx & 63;
        const float* Wsrc = (k < 64) ? w2 : ((k < 128) ? w1 : w0);
        float v = Wsrc[(k & 63) * 64 + n];
        __hip_bfloat16 h = __float2bfloat16(v);
        WThi[n * WST + k] = h;
        WTlo[n * WST + k] = __float2bfloat16(v - __bfloat162float(h));
    }
    if (t < 128) {
        int e = ebase + (t & 63);
        nidx[t] = en[2 * e + (t >> 6)];
    }

    const int r    = t >> 2;       // staging: row 0..63
    const int q    = t & 3;        // staging: k-group (8 floats at q*8)
    const int lane = t & 63;
    const int w    = t >> 6;       // wave id -> row strip
    const int mrow = lane & 15;    // A: m, B: n, D: col
    const int quad = lane >> 4;    // A/B: k-group, D: row-group

    f32x4 acc[4] = {{0,0,0,0},{0,0,0,0},{0,0,0,0},{0,0,0,0}};

    for (int ch = 0; ch < 6; ++ch) {
        const int h = ch & 1;      // which 32-col half of the 64-col source
        float4 v0, v1;
        if (ch < 2) {
            const float4* s = (const float4*)(zio + (size_t)(ebase + r) * 64 + h * 32 + q * 8);
            v0 = s[0]; v1 = s[1];
        } else if (ch < 4) {
            const float4* s = (const float4*)(x + (size_t)(ebase + r) * 64 + h * 32 + q * 8);
            v0 = s[0]; v1 = s[1];
        } else {
            const float4* sh = (const float4*)(y + (size_t)nidx[64 + r] * 64 + h * 32 + q * 8);
            const float4* st = (const float4*)(y + (size_t)nidx[r] * 64 + h * 32 + q * 8);
            float4 a0 = sh[0], a1 = sh[1], b0 = st[0], b1 = st[1];
            v0.x = a0.x - b0.x; v0.y = a0.y - b0.y; v0.z = a0.z - b0.z; v0.w = a0.w - b0.w;
            v1.x = a1.x - b1.x; v1.y = a1.y - b1.y; v1.z = a1.z - b1.z; v1.w = a1.w - b1.w;
        }
        __syncthreads();   // waves done reading previous chunk's A
        {
            float vv[8] = {v0.x, v0.y, v0.z, v0.w, v1.x, v1.y, v1.z, v1.w};
            #pragma unroll
            for (int j = 0; j < 8; ++j) {
                __hip_bfloat16 hi = __float2bfloat16(vv[j]);
                Ahi[r * AST + q * 8 + j] = hi;
                Alo[r * AST + q * 8 + j] = __float2bfloat16(vv[j] - __bfloat162float(hi));
            }
        }
        __syncthreads();   // chunk staged (first pass: also covers WT/nidx)

        const bf16x8 ah = *(const bf16x8*)&Ahi[(w * 16 + mrow) * AST + quad * 8];
        const bf16x8 al = *(const bf16x8*)&Alo[(w * 16 + mrow) * AST + quad * 8];
        #pragma unroll
        for (int nt = 0; nt < 4; ++nt) {
            const bf16x8 bh = *(const bf16x8*)&WThi[(nt * 16 + mrow) * WST + ch * 32 + quad * 8];
            const bf16x8 bl = *(const bf16x8*)&WTlo[(nt * 16 + mrow) * WST + ch * 32 + quad * 8];
            acc[nt] = __builtin_amdgcn_mfma_f32_16x16x32_bf16(ah, bh, acc[nt], 0, 0, 0);
            acc[nt] = __builtin_amdgcn_mfma_f32_16x16x32_bf16(al, bh, acc[nt], 0, 0, 0);
            acc[nt] = __builtin_amdgcn_mfma_f32_16x16x32_bf16(ah, bl, acc[nt], 0, 0, 0);
        }
    }

    // D layout: row = quad*4 + reg, col = mrow. Rows are this wave's strip.
    #pragma unroll
    for (int nt = 0; nt < 4; ++nt) {
        #pragma unroll
        for (int i = 0; i < 4; ++i) {
            int e = ebase + w * 16 + quad * 4 + i;
            int c = nt * 16 + mrow;
            zio[(size_t)e * 64 + c] = fast_tanh(acc[nt][i]);
        }
    }
}

extern "C" void kernel_launch(void* const* d_in, const int* in_sizes, int n_in,
                              void* d_out, int out_size, void* d_ws, size_t ws_size,
                              hipStream_t stream) {
    const float* x  = (const float*)d_in[0];
    const int*   en = (const int*)d_in[1];
    const int*   te = (const int*)d_in[2];
    const float* w0 = (const float*)d_in[3];
    const float* w1 = (const float*)d_in[4];
    const float* w2 = (const float*)d_in[5];
    float* out = (float*)d_out;          // doubles as z1e scratch
    float* y   = (float*)d_ws;           // 128 MB

    hipMemsetAsync(y,   0, (size_t)N_NODES * 64 * sizeof(float), stream);
    hipMemsetAsync(out, 0, (size_t)N_EDGES * 64 * sizeof(float), stream);

    k_scatter_y  <<<(N_EDGES * 64) / 256, 256, 0, stream>>>(x, en, y);
    k_scatter_z1e<<<(N_TRIS  * 64) / 256, 256, 0, stream>>>(x, te, out);
    k_final      <<<N_EDGES / 64,        256, 0, stream>>>(x, en, y, out, w0, w1, w2);
}